// Round 10
// baseline (2118.686 us; speedup 1.0000x reference)
//
#include <hip/hip_runtime.h>
#include <math.h>

// Conv3DCapsuleLayer: fp16-MFMA implicit-GEMM conv3d + fused 3-iter dynamic routing.
// input_tensor (2,24,24,24,8,32) f32 | W (3,3,3,32,256) f32 | b (1,1,1,8,32) f32
// out = activation (2,24,24,24,8,32) f32
//
// Conv rows n=0..15 map to input (b_in = n&1, ic_in = n>>1)
// Routing votes[b2][ic2] = conv row n = b2*8 + ic2
//
// Round-10 = round-9 (verified, 355us) + LDS shrink for 8 blocks/CU:
//  (1) SINGLE strip buffer (17280B; next-strip prefetch already lives in regs) —
//      one extra barrier per dz-round, paid for by 2x TLP.
//  (2) vote scratch fp16 (32 rows x 268 halves = 17152B, aliases strip; stride
//      268 puts the 4 dump write-groups on distinct banks). Votes |v|<~7 ->
//      fp16 round-trip adds ~1e-3 abs err (threshold 15e-3, current 3.9e-3).
//  (3) __launch_bounds__(256,8): VGPR=64 fits 8 waves/SIMD exactly; LDS
//      19456B x 8 = 155.6KB < 160KB. Kernel is latency-bound at 20% issue
//      utilization -> TLP is the lever.

#define SPT 13824   // 24*24*24

typedef __attribute__((ext_vector_type(8))) _Float16 half8;
typedef __attribute__((ext_vector_type(4))) float f32x4;

// reduce over a 32-lane half (masks 16,8,4,2,1) — verified rounds 1-4/8/9
__device__ __forceinline__ float redhalf(float v) {
  v += __shfl_xor(v, 16);
  v += __shfl_xor(v, 8);
  v += __shfl_xor(v, 4);
  v += __shfl_xor(v, 2);
  v += __shfl_xor(v, 1);
  return v;
}

// W (3,3,3,32,256) fp32 -> Wh[tap][cb(16)][slot(64)][8] fp16, slot = kg*16+nr:
// element (k = kg*8+j, n = cb*16+nr). This is exactly the MFMA B-fragment order.
__global__ void prep_W(const float* __restrict__ W, _Float16* __restrict__ Wh) {
  const int tap = blockIdx.x;
  #pragma unroll
  for (int rep = 0; rep < 4; ++rep) {
    const int idx = rep * 256 + threadIdx.x;   // 0..1023
    const int cb = idx >> 6;
    const int kg = (idx >> 4) & 3;
    const int nr = idx & 15;
    const int n  = cb * 16 + nr;
    half8 o;
    #pragma unroll
    for (int j = 0; j < 8; ++j)
      o[j] = (_Float16)W[(tap * 32 + kg * 8 + j) * 256 + n];
    *(half8*)(Wh + tap * 8192 + idx * 8) = o;
  }
}

__global__ __launch_bounds__(256, 8)
void caps_mfma8(const float* __restrict__ xg, const _Float16* __restrict__ Wh,
                const float* __restrict__ bg, float* __restrict__ outg) {
  // LDS: strip at 0 (17280B, single buffer).
  // Routing aliases: smVh fp16 [32][268] at 0 (17152B); smLw at 17408
  // (4 waves x 2 bufs x 64 f32 = 2048B). Total 19456B -> 8 blocks/CU.
  __shared__ __align__(16) unsigned char lds[19456];
  _Float16* smVh = (_Float16*)lds;

  const int t    = threadIdx.x;
  const int lane = t & 63;
  const int w    = t >> 6;
  // XCD-chunked swizzle: 3456 = 8 XCDs x 432 contiguous blocks
  const int wg   = (blockIdx.x & 7) * 432 + (blockIdx.x >> 3);
  const int rbase = wg * 8;
  const int b2   = rbase / SPT;
  const int posb = rbase % SPT;
  const int z  = posb / 576;
  const int y  = (posb % 576) / 24;
  const int x0 = posb % 24;

  // ---- strip staging mapping (threads 0..239) ----
  const bool stager = t < 240;
  const int sdy  = t / 80;           // 0..2
  const int srem = t % 80;
  const int sxs  = srem >> 3;        // x-slot 0..9
  const int sic  = srem & 7;         // GEMM-row ic
  const int sn   = b2 * 8 + sic;
  const int sbin = sn & 1;
  const int sicin = sn >> 1;
  const int syy  = y + sdy - 1;
  const int sxx  = x0 + sxs - 1;
  const int sR   = (sdy * 10 + sxs) * 8 + sic;      // strip row
  const bool syx_ok = (unsigned)syy < 24u && (unsigned)sxx < 24u;
  const float* sbase = xg + (((sbin * 24) * 24 + (syx_ok ? syy : 0)) * 24 + (syx_ok ? sxx : 0)) * 256 + sicin * 32;

  // ---- A-fragment lane bases (bytes within the strip) ----
  const int lm = lane & 15;
  int abase[4];
  #pragma unroll
  for (int mi = 0; mi < 4; ++mi)
    abase[mi] = ((mi * 2 + (lm >> 3)) * 8 + (lane & 7)) * 72 + (lane >> 4) * 16;

  // B fragment base: Wh + tap*8192 + (w*4+ni)*512 + lane*8  (halves)
  const _Float16* bbase = Wh + w * 2048 + lane * 8;

  f32x4 acc[4][4];
  #pragma unroll
  for (int mi = 0; mi < 4; ++mi)
    #pragma unroll
    for (int ni = 0; ni < 4; ++ni) acc[mi][ni] = (f32x4){0.f, 0.f, 0.f, 0.f};

  // ---- prologue: stage strip for dz=0 (zz = z-1) ----
  {
    const int zz = z - 1;
    const bool val = (unsigned)zz < 24u && syx_ok;
    const float* src = sbase + (zz >= 0 ? zz : 0) * 24 * 24 * 256;
    half8 h[4];
    #pragma unroll
    for (int j = 0; j < 4; ++j) {
      float4 qa = val ? *(const float4*)(src + j * 8)     : (float4){0,0,0,0};
      float4 qb = val ? *(const float4*)(src + j * 8 + 4) : (float4){0,0,0,0};
      half8 hh;
      hh[0]=(_Float16)qa.x; hh[1]=(_Float16)qa.y; hh[2]=(_Float16)qa.z; hh[3]=(_Float16)qa.w;
      hh[4]=(_Float16)qb.x; hh[5]=(_Float16)qb.y; hh[6]=(_Float16)qb.z; hh[7]=(_Float16)qb.w;
      h[j] = hh;
    }
    if (stager) {
      unsigned char* dst = lds + sR * 72;
      #pragma unroll
      for (int j = 0; j < 4; ++j) *(half8*)(dst + j * 16) = h[j];
    }
  }
  __syncthreads();

  #pragma unroll 1
  for (int dz = 0; dz < 3; ++dz) {
    // ---- issue + convert next strip (zz = z+dz) early; kept in regs ----
    half8 h[4];
    const bool have = dz < 2;
    {
      const int zz = z + dz;
      const bool val = have && (unsigned)zz < 24u && syx_ok;
      const float* src = sbase + zz * 24 * 24 * 256;
      #pragma unroll
      for (int j = 0; j < 4; ++j) {
        float4 qa = val ? *(const float4*)(src + j * 8)     : (float4){0,0,0,0};
        float4 qb = val ? *(const float4*)(src + j * 8 + 4) : (float4){0,0,0,0};
        half8 hh;
        hh[0]=(_Float16)qa.x; hh[1]=(_Float16)qa.y; hh[2]=(_Float16)qa.z; hh[3]=(_Float16)qa.w;
        hh[4]=(_Float16)qb.x; hh[5]=(_Float16)qb.y; hh[6]=(_Float16)qb.z; hh[7]=(_Float16)qb.w;
        h[j] = hh;
      }
    }

    const unsigned char* sb = lds;   // single strip buffer
    #pragma unroll 1
    for (int dy = 0; dy < 3; ++dy) {
      const _Float16* bt = bbase + (dz * 9 + dy * 3) * 8192;
      half8 bA0, bA1, bA2, bA3, bB0, bB1, bB2, bB3;
      bA0 = *(const half8*)(bt + 0 * 512);
      bA1 = *(const half8*)(bt + 1 * 512);
      bA2 = *(const half8*)(bt + 2 * 512);
      bA3 = *(const half8*)(bt + 3 * 512);

      // ---- dx = 0 (use A-set, prefetch B-set) ----
      bB0 = *(const half8*)(bt + 8192 + 0 * 512);
      bB1 = *(const half8*)(bt + 8192 + 1 * 512);
      bB2 = *(const half8*)(bt + 8192 + 2 * 512);
      bB3 = *(const half8*)(bt + 8192 + 3 * 512);
      {
        const int imm = dy * 5760;
        half8 af[4];
        #pragma unroll
        for (int mi = 0; mi < 4; ++mi) af[mi] = *(const half8*)(sb + abase[mi] + imm);
        #pragma unroll
        for (int mi = 0; mi < 4; ++mi) {
          acc[mi][0] = __builtin_amdgcn_mfma_f32_16x16x32_f16(af[mi], bA0, acc[mi][0], 0, 0, 0);
          acc[mi][1] = __builtin_amdgcn_mfma_f32_16x16x32_f16(af[mi], bA1, acc[mi][1], 0, 0, 0);
          acc[mi][2] = __builtin_amdgcn_mfma_f32_16x16x32_f16(af[mi], bA2, acc[mi][2], 0, 0, 0);
          acc[mi][3] = __builtin_amdgcn_mfma_f32_16x16x32_f16(af[mi], bA3, acc[mi][3], 0, 0, 0);
        }
      }
      // ---- dx = 1 (use B-set, prefetch A-set for dx=2) ----
      bA0 = *(const half8*)(bt + 16384 + 0 * 512);
      bA1 = *(const half8*)(bt + 16384 + 1 * 512);
      bA2 = *(const half8*)(bt + 16384 + 2 * 512);
      bA3 = *(const half8*)(bt + 16384 + 3 * 512);
      {
        const int imm = dy * 5760 + 576;
        half8 af[4];
        #pragma unroll
        for (int mi = 0; mi < 4; ++mi) af[mi] = *(const half8*)(sb + abase[mi] + imm);
        #pragma unroll
        for (int mi = 0; mi < 4; ++mi) {
          acc[mi][0] = __builtin_amdgcn_mfma_f32_16x16x32_f16(af[mi], bB0, acc[mi][0], 0, 0, 0);
          acc[mi][1] = __builtin_amdgcn_mfma_f32_16x16x32_f16(af[mi], bB1, acc[mi][1], 0, 0, 0);
          acc[mi][2] = __builtin_amdgcn_mfma_f32_16x16x32_f16(af[mi], bB2, acc[mi][2], 0, 0, 0);
          acc[mi][3] = __builtin_amdgcn_mfma_f32_16x16x32_f16(af[mi], bB3, acc[mi][3], 0, 0, 0);
        }
      }
      // ---- dx = 2 (use A-set) ----
      {
        const int imm = dy * 5760 + 1152;
        half8 af[4];
        #pragma unroll
        for (int mi = 0; mi < 4; ++mi) af[mi] = *(const half8*)(sb + abase[mi] + imm);
        #pragma unroll
        for (int mi = 0; mi < 4; ++mi) {
          acc[mi][0] = __builtin_amdgcn_mfma_f32_16x16x32_f16(af[mi], bA0, acc[mi][0], 0, 0, 0);
          acc[mi][1] = __builtin_amdgcn_mfma_f32_16x16x32_f16(af[mi], bA1, acc[mi][1], 0, 0, 0);
          acc[mi][2] = __builtin_amdgcn_mfma_f32_16x16x32_f16(af[mi], bA2, acc[mi][2], 0, 0, 0);
          acc[mi][3] = __builtin_amdgcn_mfma_f32_16x16x32_f16(af[mi], bA3, acc[mi][3], 0, 0, 0);
        }
      }
    }

    __syncthreads();             // all strip reads of this dz done
    if (have) {
      if (stager) {
        unsigned char* dst = lds + sR * 72;
        #pragma unroll
        for (int j = 0; j < 4; ++j) *(half8*)(dst + j * 16) = h[j];
      }
      __syncthreads();           // new strip visible for next dz
    }
  }

  // ---------------- routing (wave-parallel, verified round-9 structure) ----------------
  // lane = (ch = l>>5, al = l&31). Wave w routes position pl = pass*4 + w.
  // Lane owns atom al of capsules c = 2q+ch (q=0..3). Votes in fp16 LDS,
  // stride 268 halves. Logits double-buffered per wave (round-9 protocol).
  const int ch = lane >> 5;
  const int al = lane & 31;
  float* smLw = (float*)(lds + 17408) + w * 128;   // [buf][ic*8+c], buf stride 64

  float bia[4];
  #pragma unroll
  for (int q = 0; q < 4; ++q) bia[q] = bg[(2 * q + ch) * 32 + al];

  #pragma unroll 1
  for (int pass = 0; pass < 2; ++pass) {
    // dump rows [pass*32, pass*32+32) of votes (fp16, stride 268)
    #pragma unroll
    for (int mh = 0; mh < 2; ++mh) {
      const int mi = pass * 2 + mh;
      #pragma unroll
      for (int ni = 0; ni < 4; ++ni) {
        #pragma unroll
        for (int j = 0; j < 4; ++j) {
          const int rl  = mh * 16 + (lane >> 4) * 4 + j;        // 0..31
          const int col = w * 64 + ni * 16 + (lane & 15);
          smVh[rl * 268 + col] = (_Float16)acc[mi][ni][j];
        }
      }
    }
    __syncthreads();

    // this wave's position: v[ic][q] = votes[ic][capsule 2q+ch][atom al]
    float v[8][4];
    #pragma unroll
    for (int ic = 0; ic < 8; ++ic)
      #pragma unroll
      for (int q = 0; q < 4; ++q)
        v[ic][q] = (float)smVh[(w * 8 + ic) * 268 + (2 * q + ch) * 32 + al];

    #pragma unroll 1
    for (int it = 0; it < 3; ++it) {
      // preactivate (softmax from per-wave LDS table)
      const float* Lrd = smLw + ((it + 1) & 1) * 64;   // it=1 -> buf0, it=2 -> buf1
      float pre[4];
      #pragma unroll
      for (int q = 0; q < 4; ++q) pre[q] = bia[q];
      if (it == 0) {
        #pragma unroll
        for (int ic = 0; ic < 8; ++ic)
          #pragma unroll
          for (int q = 0; q < 4; ++q)
            pre[q] = fmaf(0.125f, v[ic][q], pre[q]);
      } else {
        #pragma unroll
        for (int ic = 0; ic < 8; ++ic) {
          float Lv[8];
          #pragma unroll
          for (int cc = 0; cc < 8; ++cc) Lv[cc] = Lrd[ic * 8 + cc];
          float mx = Lv[0];
          #pragma unroll
          for (int cc = 1; cc < 8; ++cc) mx = fmaxf(mx, Lv[cc]);
          float e[8];
          float s = 0.f;
          #pragma unroll
          for (int cc = 0; cc < 8; ++cc) { e[cc] = __expf(Lv[cc] - mx); s += e[cc]; }
          const float inv = 1.0f / s;
          #pragma unroll
          for (int q = 0; q < 4; ++q)
            pre[q] = fmaf(e[2 * q + ch] * inv, v[ic][q], pre[q]);
        }
      }

      // squash: norm over atoms (32-lane half reduce, verified primitive)
      float act[4];
      #pragma unroll
      for (int q = 0; q < 4; ++q) {
        float ns = redhalf(pre[q] * pre[q]);
        act[q] = pre[q] * (sqrtf(ns) / (1.0f + ns));
      }

      if (it == 2) {
        const int pl = pass * 4 + w;
        #pragma unroll
        for (int q = 0; q < 4; ++q)
          outg[(rbase + pl) * 256 + (2 * q + ch) * 32 + al] = act[q];
      } else {
        // distances (half-reduce over atoms) -> logits into write-buffer
        float d[8][4];
        #pragma unroll
        for (int ic = 0; ic < 8; ++ic)
          #pragma unroll
          for (int q = 0; q < 4; ++q)
            d[ic][q] = redhalf(v[ic][q] * act[q]);
        float* Lwr = smLw + (it & 1) * 64;           // it=0 -> buf0, it=1 -> buf1
        if (al == 0) {
          #pragma unroll
          for (int ic = 0; ic < 8; ++ic)
            #pragma unroll
            for (int q = 0; q < 4; ++q) {
              const int cc = 2 * q + ch;
              Lwr[ic * 8 + cc] = (it == 0) ? d[ic][q] : Lrd[ic * 8 + cc] + d[ic][q];
            }
        }
        __syncthreads();   // write-buffer visible; readers of old buffer unharmed
      }
    }
    // no end-of-pass barrier needed: the it1 barrier already ordered all
    // of this pass's smV reads before any wave reaches the next dump.
  }
}

// ---------------- fallback: fp32 kernel (used only if ws too small) ----------------
__global__ __launch_bounds__(256, 3)
void caps_fused(const float* __restrict__ xg, const float* __restrict__ Wg,
                const float* __restrict__ bg, float* __restrict__ outg) {
  __shared__ __align__(16) float sm[10432];
  float* smA = sm;
  float* smB = sm + 2176;
  float* smV = sm;
  float* smL = sm + 10368;

  const int t    = threadIdx.x;
  const int blk  = blockIdx.x;
  const int rbase = blk * 8;
  const int b2   = rbase / SPT;
  const int posb = rbase % SPT;
  const int z  = posb / 576;
  const int y  = (posb % 576) / 24;
  const int x0 = posb % 24;

  const int pix_t = t >> 4;
  const int oc_t  = t & 15;
  const int am    = t >> 2;
  const int acin  = (t & 3) * 8;
  const int a_pl  = am >> 3;
  const int a_n   = b2 * 8 + (am & 7);
  const int a_bin = a_n & 1;
  const int a_icin = a_n >> 1;

  float acc[4][16];
  #pragma unroll
  for (int i = 0; i < 4; ++i)
    #pragma unroll
    for (int j = 0; j < 16; ++j) acc[i][j] = 0.f;

  #pragma unroll 1
  for (int tap = 0; tap < 27; ++tap) {
    const int dz = tap / 9, dy = (tap % 9) / 3, dx = tap % 3;
    const int zz = z + dz - 1;
    const int yy = y + dy - 1;
    const int xx = x0 + a_pl + dx - 1;

    float4 va = {0.f, 0.f, 0.f, 0.f}, vb = {0.f, 0.f, 0.f, 0.f};
    if ((unsigned)zz < 24u && (unsigned)yy < 24u && (unsigned)xx < 24u) {
      const float* src = xg + ((((a_bin * 24 + zz) * 24 + yy) * 24 + xx) * 8 + a_icin) * 32 + acin;
      va = *(const float4*)src;
      vb = *(const float4*)(src + 4);
    }
    float4 wv[8];
    const float* wsrc = Wg + tap * 8192 + t * 4;
    #pragma unroll
    for (int k = 0; k < 8; ++k) wv[k] = *(const float4*)(wsrc + k * 1024);

    __syncthreads();
    smA[(acin + 0) * 68 + am] = va.x;
    smA[(acin + 1) * 68 + am] = va.y;
    smA[(acin + 2) * 68 + am] = va.z;
    smA[(acin + 3) * 68 + am] = va.w;
    smA[(acin + 4) * 68 + am] = vb.x;
    smA[(acin + 5) * 68 + am] = vb.y;
    smA[(acin + 6) * 68 + am] = vb.z;
    smA[(acin + 7) * 68 + am] = vb.w;
    #pragma unroll
    for (int k = 0; k < 8; ++k) *(float4*)&smB[k * 1024 + t * 4] = wv[k];
    __syncthreads();

    #pragma unroll 8
    for (int cin = 0; cin < 32; ++cin) {
      const float4 a4  = *(const float4*)&smA[cin * 68 + pix_t * 4];
      const float4 b0  = *(const float4*)&smB[cin * 256 + oc_t * 4];
      const float4 b1  = *(const float4*)&smB[cin * 256 + oc_t * 4 + 64];
      const float4 b2v = *(const float4*)&smB[cin * 256 + oc_t * 4 + 128];
      const float4 b3v = *(const float4*)&smB[cin * 256 + oc_t * 4 + 192];
      const float ar[4] = {a4.x, a4.y, a4.z, a4.w};
      #pragma unroll
      for (int i = 0; i < 4; ++i) {
        acc[i][0]  = fmaf(ar[i], b0.x,  acc[i][0]);
        acc[i][1]  = fmaf(ar[i], b0.y,  acc[i][1]);
        acc[i][2]  = fmaf(ar[i], b0.z,  acc[i][2]);
        acc[i][3]  = fmaf(ar[i], b0.w,  acc[i][3]);
        acc[i][4]  = fmaf(ar[i], b1.x,  acc[i][4]);
        acc[i][5]  = fmaf(ar[i], b1.y,  acc[i][5]);
        acc[i][6]  = fmaf(ar[i], b1.z,  acc[i][6]);
        acc[i][7]  = fmaf(ar[i], b1.w,  acc[i][7]);
        acc[i][8]  = fmaf(ar[i], b2v.x, acc[i][8]);
        acc[i][9]  = fmaf(ar[i], b2v.y, acc[i][9]);
        acc[i][10] = fmaf(ar[i], b2v.z, acc[i][10]);
        acc[i][11] = fmaf(ar[i], b2v.w, acc[i][11]);
        acc[i][12] = fmaf(ar[i], b3v.x, acc[i][12]);
        acc[i][13] = fmaf(ar[i], b3v.y, acc[i][13]);
        acc[i][14] = fmaf(ar[i], b3v.z, acc[i][14]);
        acc[i][15] = fmaf(ar[i], b3v.w, acc[i][15]);
      }
    }
  }
  __syncthreads();

  const int c = t >> 5;
  const int a = t & 31;
  const float bia = bg[t];

  #pragma unroll 1
  for (int pass = 0; pass < 2; ++pass) {
    if ((pix_t >> 3) == pass) {
      const int rl = (pix_t & 7) * 4;
      #pragma unroll
      for (int i = 0; i < 4; ++i) {
        #pragma unroll
        for (int jj = 0; jj < 4; ++jj) {
          float4 v4 = {acc[i][jj * 4 + 0], acc[i][jj * 4 + 1],
                       acc[i][jj * 4 + 2], acc[i][jj * 4 + 3]};
          *(float4*)&smV[(rl + i) * 256 + oc_t * 4 + jj * 64] = v4;
        }
      }
    }
    __syncthreads();

    #pragma unroll 1
    for (int pp = 0; pp < 4; ++pp) {
      const int pl = pass * 4 + pp;
      float v[8];
      #pragma unroll
      for (int ic = 0; ic < 8; ++ic) v[ic] = smV[(pp * 8 + ic) * 256 + t];

      float route[8];
      #pragma unroll 1
      for (int it = 0; it < 3; ++it) {
        if (it == 0) {
          #pragma unroll
          for (int ic = 0; ic < 8; ++ic) route[ic] = 0.125f;
        } else {
          #pragma unroll
          for (int ic = 0; ic < 8; ++ic) {
            float mx = -3.4e38f;
            #pragma unroll
            for (int cc = 0; cc < 8; ++cc) mx = fmaxf(mx, smL[ic * 8 + cc]);
            float s = 0.f;
            #pragma unroll
            for (int cc = 0; cc < 8; ++cc) s += __expf(smL[ic * 8 + cc] - mx);
            route[ic] = __expf(smL[ic * 8 + c] - mx) / s;
          }
        }
        float pre = bia;
        #pragma unroll
        for (int ic = 0; ic < 8; ++ic) pre = fmaf(route[ic], v[ic], pre);

        float ns = redhalf(pre * pre);
        const float nrm = sqrtf(ns);
        const float act = pre * (nrm / (1.0f + ns));

        if (it == 2) {
          outg[(rbase + pl) * 256 + t] = act;
        } else {
          float d[8];
          #pragma unroll
          for (int ic = 0; ic < 8; ++ic) d[ic] = redhalf(v[ic] * act);
          __syncthreads();
          if (a == 0) {
            #pragma unroll
            for (int ic = 0; ic < 8; ++ic)
              smL[ic * 8 + c] = (it == 0) ? d[ic] : smL[ic * 8 + c] + d[ic];
          }
          __syncthreads();
        }
      }
    }
    __syncthreads();
  }
}

extern "C" void kernel_launch(void* const* d_in, const int* in_sizes, int n_in,
                              void* d_out, int out_size, void* d_ws, size_t ws_size,
                              hipStream_t stream) {
  const float* x = (const float*)d_in[0];
  const float* W = (const float*)d_in[1];
  const float* b = (const float*)d_in[2];
  float* out = (float*)d_out;
  (void)in_sizes; (void)n_in; (void)out_size;

  if (ws_size >= 27u * 8192u * sizeof(_Float16)) {
    _Float16* Wh = (_Float16*)d_ws;
    prep_W<<<dim3(27), dim3(256), 0, stream>>>(W, Wh);
    caps_mfma8<<<dim3(3456), dim3(256), 0, stream>>>(x, Wh, b, out);
  } else {
    caps_fused<<<dim3(3456), dim3(256), 0, stream>>>(x, W, b, out);
  }
}

// Round 12
// 817.475 us; speedup vs baseline: 2.5917x; 2.5917x over previous
//
#include <hip/hip_runtime.h>
#include <math.h>

// Conv3DCapsuleLayer: fp16-MFMA implicit-GEMM conv3d + fused 3-iter dynamic routing.
// input_tensor (2,24,24,24,8,32) f32 | W (3,3,3,32,256) f32 | b (1,1,1,8,32) f32
// out = activation (2,24,24,24,8,32) f32
//
// Conv rows n=0..15 map to input (b_in = n&1, ic_in = n>>1)
// Routing votes[b2][ic2] = conv row n = b2*8 + ic2
//
// Round-12 = round-11 with the compile fix (__exp2f does not exist as a HIP
// device builtin -> use __expf, verified in all passing rounds). Structure:
// round-9 base (355us verified; lb(256,4) — r10 proved 8 waves/SIMD spills) +
//  (1) flattened 9-tap pipeline per dz: P/Q register double-buffer for B
//      fragments — tap k+1 loads issue before tap k MFMAs (27 -> 3 exposed
//      L2 latencies per wave per block).
//  (2) softmax logits read as 2x ds_read_b128 (was 64 scalar reads/it).
//  (3) routing memory layout/protocol byte-identical to round 9.

#define SPT 13824   // 24*24*24

typedef __attribute__((ext_vector_type(8))) _Float16 half8;
typedef __attribute__((ext_vector_type(4))) float f32x4;

// reduce over a 32-lane half (masks 16,8,4,2,1) — verified rounds 1-4/8/9
__device__ __forceinline__ float redhalf(float v) {
  v += __shfl_xor(v, 16);
  v += __shfl_xor(v, 8);
  v += __shfl_xor(v, 4);
  v += __shfl_xor(v, 2);
  v += __shfl_xor(v, 1);
  return v;
}

// W (3,3,3,32,256) fp32 -> Wh[tap][cb(16)][slot(64)][8] fp16, slot = kg*16+nr:
// element (k = kg*8+j, n = cb*16+nr). This is exactly the MFMA B-fragment order.
__global__ void prep_W(const float* __restrict__ W, _Float16* __restrict__ Wh) {
  const int tap = blockIdx.x;
  #pragma unroll
  for (int rep = 0; rep < 4; ++rep) {
    const int idx = rep * 256 + threadIdx.x;   // 0..1023
    const int cb = idx >> 6;
    const int kg = (idx >> 4) & 3;
    const int nr = idx & 15;
    const int n  = cb * 16 + nr;
    half8 o;
    #pragma unroll
    for (int j = 0; j < 8; ++j)
      o[j] = (_Float16)W[(tap * 32 + kg * 8 + j) * 256 + n];
    *(half8*)(Wh + tap * 8192 + idx * 8) = o;
  }
}

__global__ __launch_bounds__(256, 4)
void caps_mfma9(const float* __restrict__ xg, const _Float16* __restrict__ Wh,
                const float* __restrict__ bg, float* __restrict__ outg) {
  // LDS: strip buf0 at 0, buf1 at 17280 (each 17280B); routing aliases:
  // smV f32 [32][264] at 0 (33792B), smLw 4 waves x 2 bufs x 64 f32 at 33792 (2048B)
  __shared__ __align__(16) unsigned char lds[35840];
  float* smV = (float*)lds;

  const int t    = threadIdx.x;
  const int lane = t & 63;
  const int w    = t >> 6;
  // XCD-chunked swizzle: 3456 = 8 XCDs x 432 contiguous blocks
  const int wg   = (blockIdx.x & 7) * 432 + (blockIdx.x >> 3);
  const int rbase = wg * 8;
  const int b2   = rbase / SPT;
  const int posb = rbase % SPT;
  const int z  = posb / 576;
  const int y  = (posb % 576) / 24;
  const int x0 = posb % 24;

  // ---- strip staging mapping (threads 0..239) ----
  const bool stager = t < 240;
  const int sdy  = t / 80;           // 0..2
  const int srem = t % 80;
  const int sxs  = srem >> 3;        // x-slot 0..9
  const int sic  = srem & 7;         // GEMM-row ic
  const int sn   = b2 * 8 + sic;
  const int sbin = sn & 1;
  const int sicin = sn >> 1;
  const int syy  = y + sdy - 1;
  const int sxx  = x0 + sxs - 1;
  const int sR   = (sdy * 10 + sxs) * 8 + sic;      // strip row
  const bool syx_ok = (unsigned)syy < 24u && (unsigned)sxx < 24u;
  const float* sbase = xg + (((sbin * 24) * 24 + (syx_ok ? syy : 0)) * 24 + (syx_ok ? sxx : 0)) * 256 + sicin * 32;

  // ---- A-fragment lane bases (bytes within a strip buffer) ----
  const int lm = lane & 15;
  int abase[4];
  #pragma unroll
  for (int mi = 0; mi < 4; ++mi)
    abase[mi] = ((mi * 2 + (lm >> 3)) * 8 + (lane & 7)) * 72 + (lane >> 4) * 16;

  // B fragment base: Wh + tap*8192 + (w*4+ni)*512 + lane*8  (halves)
  const _Float16* bbase = Wh + w * 2048 + lane * 8;

  f32x4 acc[4][4];
  #pragma unroll
  for (int mi = 0; mi < 4; ++mi)
    #pragma unroll
    for (int ni = 0; ni < 4; ++ni) acc[mi][ni] = (f32x4){0.f, 0.f, 0.f, 0.f};

  // ---- prologue: stage strip for dz=0 (zz = z-1) into buf0 ----
  {
    const int zz = z - 1;
    const bool val = (unsigned)zz < 24u && syx_ok;
    const float* src = sbase + (zz >= 0 ? zz : 0) * 24 * 24 * 256;
    half8 h[4];
    #pragma unroll
    for (int j = 0; j < 4; ++j) {
      float4 qa = val ? *(const float4*)(src + j * 8)     : (float4){0,0,0,0};
      float4 qb = val ? *(const float4*)(src + j * 8 + 4) : (float4){0,0,0,0};
      half8 hh;
      hh[0]=(_Float16)qa.x; hh[1]=(_Float16)qa.y; hh[2]=(_Float16)qa.z; hh[3]=(_Float16)qa.w;
      hh[4]=(_Float16)qb.x; hh[5]=(_Float16)qb.y; hh[6]=(_Float16)qb.z; hh[7]=(_Float16)qb.w;
      h[j] = hh;
    }
    if (stager) {
      unsigned char* dst = lds + sR * 72;
      #pragma unroll
      for (int j = 0; j < 4; ++j) *(half8*)(dst + j * 16) = h[j];
    }
  }
  __syncthreads();

  #pragma unroll 1
  for (int dz = 0; dz < 3; ++dz) {
    // ---- issue + convert next strip (zz = z+dz) early ----
    half8 h[4];
    const bool have = dz < 2;
    {
      const int zz = z + dz;
      const bool val = have && (unsigned)zz < 24u && syx_ok;
      const float* src = sbase + zz * 24 * 24 * 256;
      #pragma unroll
      for (int j = 0; j < 4; ++j) {
        float4 qa = val ? *(const float4*)(src + j * 8)     : (float4){0,0,0,0};
        float4 qb = val ? *(const float4*)(src + j * 8 + 4) : (float4){0,0,0,0};
        half8 hh;
        hh[0]=(_Float16)qa.x; hh[1]=(_Float16)qa.y; hh[2]=(_Float16)qa.z; hh[3]=(_Float16)qa.w;
        hh[4]=(_Float16)qb.x; hh[5]=(_Float16)qb.y; hh[6]=(_Float16)qb.z; hh[7]=(_Float16)qb.w;
        h[j] = hh;
      }
    }

    // ---- 9-tap flattened pipeline: P/Q register double-buffer for B ----
    const unsigned char* sb = lds + (dz & 1) * 17280;
    const _Float16* btz = bbase + dz * 9 * 8192;
    half8 bP0, bP1, bP2, bP3, bQ0, bQ1, bQ2, bQ3;
    bP0 = *(const half8*)(btz + 0 * 512);
    bP1 = *(const half8*)(btz + 1 * 512);
    bP2 = *(const half8*)(btz + 2 * 512);
    bP3 = *(const half8*)(btz + 3 * 512);

    #pragma unroll
    for (int k = 0; k < 9; ++k) {
      // prefetch tap k+1 into the other register set (hides L2 latency
      // under tap k's 16 MFMAs)
      if (k < 8) {
        const _Float16* nb = btz + (k + 1) * 8192;
        if ((k & 1) == 0) {
          bQ0 = *(const half8*)(nb + 0 * 512);
          bQ1 = *(const half8*)(nb + 1 * 512);
          bQ2 = *(const half8*)(nb + 2 * 512);
          bQ3 = *(const half8*)(nb + 3 * 512);
        } else {
          bP0 = *(const half8*)(nb + 0 * 512);
          bP1 = *(const half8*)(nb + 1 * 512);
          bP2 = *(const half8*)(nb + 2 * 512);
          bP3 = *(const half8*)(nb + 3 * 512);
        }
      }
      const int imm = ((k / 3) * 10 + (k % 3)) * 576;   // compile-time (unrolled)
      half8 af[4];
      #pragma unroll
      for (int mi = 0; mi < 4; ++mi) af[mi] = *(const half8*)(sb + abase[mi] + imm);
      if ((k & 1) == 0) {
        #pragma unroll
        for (int mi = 0; mi < 4; ++mi) {
          acc[mi][0] = __builtin_amdgcn_mfma_f32_16x16x32_f16(af[mi], bP0, acc[mi][0], 0, 0, 0);
          acc[mi][1] = __builtin_amdgcn_mfma_f32_16x16x32_f16(af[mi], bP1, acc[mi][1], 0, 0, 0);
          acc[mi][2] = __builtin_amdgcn_mfma_f32_16x16x32_f16(af[mi], bP2, acc[mi][2], 0, 0, 0);
          acc[mi][3] = __builtin_amdgcn_mfma_f32_16x16x32_f16(af[mi], bP3, acc[mi][3], 0, 0, 0);
        }
      } else {
        #pragma unroll
        for (int mi = 0; mi < 4; ++mi) {
          acc[mi][0] = __builtin_amdgcn_mfma_f32_16x16x32_f16(af[mi], bQ0, acc[mi][0], 0, 0, 0);
          acc[mi][1] = __builtin_amdgcn_mfma_f32_16x16x32_f16(af[mi], bQ1, acc[mi][1], 0, 0, 0);
          acc[mi][2] = __builtin_amdgcn_mfma_f32_16x16x32_f16(af[mi], bQ2, acc[mi][2], 0, 0, 0);
          acc[mi][3] = __builtin_amdgcn_mfma_f32_16x16x32_f16(af[mi], bQ3, acc[mi][3], 0, 0, 0);
        }
      }
    }

    if (have && stager) {
      unsigned char* dst = lds + ((dz + 1) & 1) * 17280 + sR * 72;
      #pragma unroll
      for (int j = 0; j < 4; ++j) *(half8*)(dst + j * 16) = h[j];
    }
    __syncthreads();
  }

  // ---------------- routing (wave-parallel, verified round-9 structure) ----------------
  // lane = (ch = l>>5, al = l&31). Wave w routes position pl = pass*4 + w.
  // Lane owns atom al of capsules c = 2q+ch (q=0..3).
  // Logits: per-wave 8x8 table in LDS, double-buffered (round-9 protocol).
  const int ch = lane >> 5;
  const int al = lane & 31;
  float* smLw = (float*)(lds + 33792) + w * 128;   // [buf][ic*8+c], buf stride 64

  float bia[4];
  #pragma unroll
  for (int q = 0; q < 4; ++q) bia[q] = bg[(2 * q + ch) * 32 + al];

  #pragma unroll 1
  for (int pass = 0; pass < 2; ++pass) {
    // dump rows [pass*32, pass*32+32) of votes — verbatim round-4/9 dump
    #pragma unroll
    for (int mh = 0; mh < 2; ++mh) {
      const int mi = pass * 2 + mh;
      #pragma unroll
      for (int ni = 0; ni < 4; ++ni) {
        #pragma unroll
        for (int j = 0; j < 4; ++j) {
          const int rl  = mh * 16 + (lane >> 4) * 4 + j;        // 0..31
          const int col = w * 64 + ni * 16 + (lane & 15);
          smV[rl * 264 + col] = acc[mi][ni][j];
        }
      }
    }
    __syncthreads();

    // this wave's position: v[ic][q] = votes[ic][capsule 2q+ch][atom al]
    float v[8][4];
    #pragma unroll
    for (int ic = 0; ic < 8; ++ic)
      #pragma unroll
      for (int q = 0; q < 4; ++q)
        v[ic][q] = smV[(w * 8 + ic) * 264 + (2 * q + ch) * 32 + al];

    #pragma unroll 1
    for (int it = 0; it < 3; ++it) {
      // preactivate (softmax from per-wave LDS table)
      const float* Lrd = smLw + ((it + 1) & 1) * 64;   // it=1 -> buf0, it=2 -> buf1
      float pre[4];
      #pragma unroll
      for (int q = 0; q < 4; ++q) pre[q] = bia[q];
      if (it == 0) {
        #pragma unroll
        for (int ic = 0; ic < 8; ++ic)
          #pragma unroll
          for (int q = 0; q < 4; ++q)
            pre[q] = fmaf(0.125f, v[ic][q], pre[q]);
      } else {
        #pragma unroll
        for (int ic = 0; ic < 8; ++ic) {
          const float4 La = *(const float4*)(Lrd + ic * 8);
          const float4 Lb = *(const float4*)(Lrd + ic * 8 + 4);
          const float Lv[8] = {La.x, La.y, La.z, La.w, Lb.x, Lb.y, Lb.z, Lb.w};
          float mx = Lv[0];
          #pragma unroll
          for (int cc = 1; cc < 8; ++cc) mx = fmaxf(mx, Lv[cc]);
          float e[8];
          float s = 0.f;
          #pragma unroll
          for (int cc = 0; cc < 8; ++cc) { e[cc] = __expf(Lv[cc] - mx); s += e[cc]; }
          const float inv = 1.0f / s;
          #pragma unroll
          for (int q = 0; q < 4; ++q)
            pre[q] = fmaf(e[2 * q + ch] * inv, v[ic][q], pre[q]);
        }
      }

      // squash: norm over atoms (32-lane half reduce, verified primitive)
      float act[4];
      #pragma unroll
      for (int q = 0; q < 4; ++q) {
        float ns = redhalf(pre[q] * pre[q]);
        act[q] = pre[q] * (sqrtf(ns) / (1.0f + ns));
      }

      if (it == 2) {
        const int pl = pass * 4 + w;
        #pragma unroll
        for (int q = 0; q < 4; ++q)
          outg[(rbase + pl) * 256 + (2 * q + ch) * 32 + al] = act[q];
      } else {
        // distances (half-reduce over atoms) -> logits into write-buffer
        float d[8][4];
        #pragma unroll
        for (int ic = 0; ic < 8; ++ic)
          #pragma unroll
          for (int q = 0; q < 4; ++q)
            d[ic][q] = redhalf(v[ic][q] * act[q]);
        float* Lwr = smLw + (it & 1) * 64;           // it=0 -> buf0, it=1 -> buf1
        if (al == 0) {
          #pragma unroll
          for (int ic = 0; ic < 8; ++ic)
            #pragma unroll
            for (int q = 0; q < 4; ++q) {
              const int cc = 2 * q + ch;
              Lwr[ic * 8 + cc] = (it == 0) ? d[ic][q] : Lrd[ic * 8 + cc] + d[ic][q];
            }
        }
        __syncthreads();   // write-buffer visible; readers of old buffer unharmed
      }
    }
    // no end-of-pass barrier needed: the it1 barrier already ordered all
    // of this pass's smV reads before any wave reaches the next dump.
  }
}

// ---------------- fallback: fp32 kernel (used only if ws too small) ----------------
__global__ __launch_bounds__(256, 3)
void caps_fused(const float* __restrict__ xg, const float* __restrict__ Wg,
                const float* __restrict__ bg, float* __restrict__ outg) {
  __shared__ __align__(16) float sm[10432];
  float* smA = sm;
  float* smB = sm + 2176;
  float* smV = sm;
  float* smL = sm + 10368;

  const int t    = threadIdx.x;
  const int blk  = blockIdx.x;
  const int rbase = blk * 8;
  const int b2   = rbase / SPT;
  const int posb = rbase % SPT;
  const int z  = posb / 576;
  const int y  = (posb % 576) / 24;
  const int x0 = posb % 24;

  const int pix_t = t >> 4;
  const int oc_t  = t & 15;
  const int am    = t >> 2;
  const int acin  = (t & 3) * 8;
  const int a_pl  = am >> 3;
  const int a_n   = b2 * 8 + (am & 7);
  const int a_bin = a_n & 1;
  const int a_icin = a_n >> 1;

  float acc[4][16];
  #pragma unroll
  for (int i = 0; i < 4; ++i)
    #pragma unroll
    for (int j = 0; j < 16; ++j) acc[i][j] = 0.f;

  #pragma unroll 1
  for (int tap = 0; tap < 27; ++tap) {
    const int dz = tap / 9, dy = (tap % 9) / 3, dx = tap % 3;
    const int zz = z + dz - 1;
    const int yy = y + dy - 1;
    const int xx = x0 + a_pl + dx - 1;

    float4 va = {0.f, 0.f, 0.f, 0.f}, vb = {0.f, 0.f, 0.f, 0.f};
    if ((unsigned)zz < 24u && (unsigned)yy < 24u && (unsigned)xx < 24u) {
      const float* src = xg + ((((a_bin * 24 + zz) * 24 + yy) * 24 + xx) * 8 + a_icin) * 32 + acin;
      va = *(const float4*)src;
      vb = *(const float4*)(src + 4);
    }
    float4 wv[8];
    const float* wsrc = Wg + tap * 8192 + t * 4;
    #pragma unroll
    for (int k = 0; k < 8; ++k) wv[k] = *(const float4*)(wsrc + k * 1024);

    __syncthreads();
    smA[(acin + 0) * 68 + am] = va.x;
    smA[(acin + 1) * 68 + am] = va.y;
    smA[(acin + 2) * 68 + am] = va.z;
    smA[(acin + 3) * 68 + am] = va.w;
    smA[(acin + 4) * 68 + am] = vb.x;
    smA[(acin + 5) * 68 + am] = vb.y;
    smA[(acin + 6) * 68 + am] = vb.z;
    smA[(acin + 7) * 68 + am] = vb.w;
    #pragma unroll
    for (int k = 0; k < 8; ++k) *(float4*)&smB[k * 1024 + t * 4] = wv[k];
    __syncthreads();

    #pragma unroll 8
    for (int cin = 0; cin < 32; ++cin) {
      const float4 a4  = *(const float4*)&smA[cin * 68 + pix_t * 4];
      const float4 b0  = *(const float4*)&smB[cin * 256 + oc_t * 4];
      const float4 b1  = *(const float4*)&smB[cin * 256 + oc_t * 4 + 64];
      const float4 b2v = *(const float4*)&smB[cin * 256 + oc_t * 4 + 128];
      const float4 b3v = *(const float4*)&smB[cin * 256 + oc_t * 4 + 192];
      const float ar[4] = {a4.x, a4.y, a4.z, a4.w};
      #pragma unroll
      for (int i = 0; i < 4; ++i) {
        acc[i][0]  = fmaf(ar[i], b0.x,  acc[i][0]);
        acc[i][1]  = fmaf(ar[i], b0.y,  acc[i][1]);
        acc[i][2]  = fmaf(ar[i], b0.z,  acc[i][2]);
        acc[i][3]  = fmaf(ar[i], b0.w,  acc[i][3]);
        acc[i][4]  = fmaf(ar[i], b1.x,  acc[i][4]);
        acc[i][5]  = fmaf(ar[i], b1.y,  acc[i][5]);
        acc[i][6]  = fmaf(ar[i], b1.z,  acc[i][6]);
        acc[i][7]  = fmaf(ar[i], b1.w,  acc[i][7]);
        acc[i][8]  = fmaf(ar[i], b2v.x, acc[i][8]);
        acc[i][9]  = fmaf(ar[i], b2v.y, acc[i][9]);
        acc[i][10] = fmaf(ar[i], b2v.z, acc[i][10]);
        acc[i][11] = fmaf(ar[i], b2v.w, acc[i][11]);
        acc[i][12] = fmaf(ar[i], b3v.x, acc[i][12]);
        acc[i][13] = fmaf(ar[i], b3v.y, acc[i][13]);
        acc[i][14] = fmaf(ar[i], b3v.z, acc[i][14]);
        acc[i][15] = fmaf(ar[i], b3v.w, acc[i][15]);
      }
    }
  }
  __syncthreads();

  const int c = t >> 5;
  const int a = t & 31;
  const float bia = bg[t];

  #pragma unroll 1
  for (int pass = 0; pass < 2; ++pass) {
    if ((pix_t >> 3) == pass) {
      const int rl = (pix_t & 7) * 4;
      #pragma unroll
      for (int i = 0; i < 4; ++i) {
        #pragma unroll
        for (int jj = 0; jj < 4; ++jj) {
          float4 v4 = {acc[i][jj * 4 + 0], acc[i][jj * 4 + 1],
                       acc[i][jj * 4 + 2], acc[i][jj * 4 + 3]};
          *(float4*)&smV[(rl + i) * 256 + oc_t * 4 + jj * 64] = v4;
        }
      }
    }
    __syncthreads();

    #pragma unroll 1
    for (int pp = 0; pp < 4; ++pp) {
      const int pl = pass * 4 + pp;
      float v[8];
      #pragma unroll
      for (int ic = 0; ic < 8; ++ic) v[ic] = smV[(pp * 8 + ic) * 256 + t];

      float route[8];
      #pragma unroll 1
      for (int it = 0; it < 3; ++it) {
        if (it == 0) {
          #pragma unroll
          for (int ic = 0; ic < 8; ++ic) route[ic] = 0.125f;
        } else {
          #pragma unroll
          for (int ic = 0; ic < 8; ++ic) {
            float mx = -3.4e38f;
            #pragma unroll
            for (int cc = 0; cc < 8; ++cc) mx = fmaxf(mx, smL[ic * 8 + cc]);
            float s = 0.f;
            #pragma unroll
            for (int cc = 0; cc < 8; ++cc) s += __expf(smL[ic * 8 + cc] - mx);
            route[ic] = __expf(smL[ic * 8 + c] - mx) / s;
          }
        }
        float pre = bia;
        #pragma unroll
        for (int ic = 0; ic < 8; ++ic) pre = fmaf(route[ic], v[ic], pre);

        float ns = redhalf(pre * pre);
        const float nrm = sqrtf(ns);
        const float act = pre * (nrm / (1.0f + ns));

        if (it == 2) {
          outg[(rbase + pl) * 256 + t] = act;
        } else {
          float d[8];
          #pragma unroll
          for (int ic = 0; ic < 8; ++ic) d[ic] = redhalf(v[ic] * act);
          __syncthreads();
          if (a == 0) {
            #pragma unroll
            for (int ic = 0; ic < 8; ++ic)
              smL[ic * 8 + c] = (it == 0) ? d[ic] : smL[ic * 8 + c] + d[ic];
          }
          __syncthreads();
        }
      }
    }
    __syncthreads();
  }
}

extern "C" void kernel_launch(void* const* d_in, const int* in_sizes, int n_in,
                              void* d_out, int out_size, void* d_ws, size_t ws_size,
                              hipStream_t stream) {
  const float* x = (const float*)d_in[0];
  const float* W = (const float*)d_in[1];
  const float* b = (const float*)d_in[2];
  float* out = (float*)d_out;
  (void)in_sizes; (void)n_in; (void)out_size;

  if (ws_size >= 27u * 8192u * sizeof(_Float16)) {
    _Float16* Wh = (_Float16*)d_ws;
    prep_W<<<dim3(27), dim3(256), 0, stream>>>(W, Wh);
    caps_mfma9<<<dim3(3456), dim3(256), 0, stream>>>(x, Wh, b, out);
  } else {
    caps_fused<<<dim3(3456), dim3(256), 0, stream>>>(x, W, b, out);
  }
}

// Round 13
// 328.662 us; speedup vs baseline: 6.4464x; 2.4873x over previous
//
#include <hip/hip_runtime.h>
#include <math.h>

// Conv3DCapsuleLayer: fp16-MFMA implicit-GEMM conv3d + 3-iter dynamic routing.
// input_tensor (2,24,24,24,8,32) f32 | W (3,3,3,32,256) f32 | b (1,1,1,8,32) f32
// out = activation (2,24,24,24,8,32) f32
//
// Conv rows n=0..15 map to input (b_in = n&1, ic_in = n>>1)
// Routing votes[b2][ic2] = conv row n = b2*8 + ic2
//
// Round-13: SPLIT into conv + routing kernels (r12's unrolled prefetch spilled:
// WRITE_SIZE 4.1GB scratch traffic at VGPR=64 — revert GEMM to r9's verified
// dy-loop form).
//  A) caps_conv: r9 GEMM verbatim; stores votes fp16 direct from acc to d_ws
//     (fp16 votes validated r10). No routing tail, no smV phase.
//  B) caps_route: r9's verified wave-local routing verbatim, 1 position/wave,
//     6912 blocks -> 27 blocks/CU TLP; coalesced vote reads.
// Fallbacks: ws>=114MB split | ws>=432KB r9-fused (355us verified) | fp32.

#define SPT 13824   // 24*24*24

typedef __attribute__((ext_vector_type(8))) _Float16 half8;
typedef __attribute__((ext_vector_type(4))) float f32x4;

// reduce over a 32-lane half (masks 16,8,4,2,1) — verified rounds 1-4/8/9
__device__ __forceinline__ float redhalf(float v) {
  v += __shfl_xor(v, 16);
  v += __shfl_xor(v, 8);
  v += __shfl_xor(v, 4);
  v += __shfl_xor(v, 2);
  v += __shfl_xor(v, 1);
  return v;
}

// W (3,3,3,32,256) fp32 -> Wh[tap][cb(16)][slot(64)][8] fp16, slot = kg*16+nr:
// element (k = kg*8+j, n = cb*16+nr). This is exactly the MFMA B-fragment order.
__global__ void prep_W(const float* __restrict__ W, _Float16* __restrict__ Wh) {
  const int tap = blockIdx.x;
  #pragma unroll
  for (int rep = 0; rep < 4; ++rep) {
    const int idx = rep * 256 + threadIdx.x;   // 0..1023
    const int cb = idx >> 6;
    const int kg = (idx >> 4) & 3;
    const int nr = idx & 15;
    const int n  = cb * 16 + nr;
    half8 o;
    #pragma unroll
    for (int j = 0; j < 8; ++j)
      o[j] = (_Float16)W[(tap * 32 + kg * 8 + j) * 256 + n];
    *(half8*)(Wh + tap * 8192 + idx * 8) = o;
  }
}

// ================= kernel A: conv GEMM (r9 structure verbatim) ==============
__global__ __launch_bounds__(256, 4)
void caps_conv(const float* __restrict__ xg, const _Float16* __restrict__ Wh,
               _Float16* __restrict__ vws) {
  // LDS: strip buf0 at 0, buf1 at 17280 (each 17280B). 34560B total.
  __shared__ __align__(16) unsigned char lds[34560];

  const int t    = threadIdx.x;
  const int lane = t & 63;
  const int w    = t >> 6;
  // XCD-chunked swizzle: 3456 = 8 XCDs x 432 contiguous blocks
  const int wg   = (blockIdx.x & 7) * 432 + (blockIdx.x >> 3);
  const int rbase = wg * 8;
  const int b2   = rbase / SPT;
  const int posb = rbase % SPT;
  const int z  = posb / 576;
  const int y  = (posb % 576) / 24;
  const int x0 = posb % 24;

  // ---- strip staging mapping (threads 0..239) ----
  const bool stager = t < 240;
  const int sdy  = t / 80;           // 0..2
  const int srem = t % 80;
  const int sxs  = srem >> 3;        // x-slot 0..9
  const int sic  = srem & 7;         // GEMM-row ic
  const int sn   = b2 * 8 + sic;
  const int sbin = sn & 1;
  const int sicin = sn >> 1;
  const int syy  = y + sdy - 1;
  const int sxx  = x0 + sxs - 1;
  const int sR   = (sdy * 10 + sxs) * 8 + sic;      // strip row
  const bool syx_ok = (unsigned)syy < 24u && (unsigned)sxx < 24u;
  const float* sbase = xg + (((sbin * 24) * 24 + (syx_ok ? syy : 0)) * 24 + (syx_ok ? sxx : 0)) * 256 + sicin * 32;

  // ---- A-fragment lane bases (bytes within a strip buffer) ----
  const int lm = lane & 15;
  int abase[4];
  #pragma unroll
  for (int mi = 0; mi < 4; ++mi)
    abase[mi] = ((mi * 2 + (lm >> 3)) * 8 + (lane & 7)) * 72 + (lane >> 4) * 16;

  // B fragment base: Wh + tap*8192 + (w*4+ni)*512 + lane*8  (halves)
  const _Float16* bbase = Wh + w * 2048 + lane * 8;

  f32x4 acc[4][4];
  #pragma unroll
  for (int mi = 0; mi < 4; ++mi)
    #pragma unroll
    for (int ni = 0; ni < 4; ++ni) acc[mi][ni] = (f32x4){0.f, 0.f, 0.f, 0.f};

  // ---- prologue: stage strip for dz=0 (zz = z-1) into buf0 ----
  {
    const int zz = z - 1;
    const bool val = (unsigned)zz < 24u && syx_ok;
    const float* src = sbase + (zz >= 0 ? zz : 0) * 24 * 24 * 256;
    half8 h[4];
    #pragma unroll
    for (int j = 0; j < 4; ++j) {
      float4 qa = val ? *(const float4*)(src + j * 8)     : (float4){0,0,0,0};
      float4 qb = val ? *(const float4*)(src + j * 8 + 4) : (float4){0,0,0,0};
      half8 hh;
      hh[0]=(_Float16)qa.x; hh[1]=(_Float16)qa.y; hh[2]=(_Float16)qa.z; hh[3]=(_Float16)qa.w;
      hh[4]=(_Float16)qb.x; hh[5]=(_Float16)qb.y; hh[6]=(_Float16)qb.z; hh[7]=(_Float16)qb.w;
      h[j] = hh;
    }
    if (stager) {
      unsigned char* dst = lds + sR * 72;
      #pragma unroll
      for (int j = 0; j < 4; ++j) *(half8*)(dst + j * 16) = h[j];
    }
  }
  __syncthreads();

  #pragma unroll 1
  for (int dz = 0; dz < 3; ++dz) {
    // ---- issue + convert next strip (zz = z+dz) early ----
    half8 h[4];
    const bool have = dz < 2;
    {
      const int zz = z + dz;
      const bool val = have && (unsigned)zz < 24u && syx_ok;
      const float* src = sbase + zz * 24 * 24 * 256;
      #pragma unroll
      for (int j = 0; j < 4; ++j) {
        float4 qa = val ? *(const float4*)(src + j * 8)     : (float4){0,0,0,0};
        float4 qb = val ? *(const float4*)(src + j * 8 + 4) : (float4){0,0,0,0};
        half8 hh;
        hh[0]=(_Float16)qa.x; hh[1]=(_Float16)qa.y; hh[2]=(_Float16)qa.z; hh[3]=(_Float16)qa.w;
        hh[4]=(_Float16)qb.x; hh[5]=(_Float16)qb.y; hh[6]=(_Float16)qb.z; hh[7]=(_Float16)qb.w;
        h[j] = hh;
      }
    }

    const unsigned char* sb = lds + (dz & 1) * 17280;
    #pragma unroll 1
    for (int dy = 0; dy < 3; ++dy) {
      const _Float16* bt = bbase + (dz * 9 + dy * 3) * 8192;
      half8 bA0, bA1, bA2, bA3, bB0, bB1, bB2, bB3;
      bA0 = *(const half8*)(bt + 0 * 512);
      bA1 = *(const half8*)(bt + 1 * 512);
      bA2 = *(const half8*)(bt + 2 * 512);
      bA3 = *(const half8*)(bt + 3 * 512);

      // ---- dx = 0 (use A-set, prefetch B-set) ----
      bB0 = *(const half8*)(bt + 8192 + 0 * 512);
      bB1 = *(const half8*)(bt + 8192 + 1 * 512);
      bB2 = *(const half8*)(bt + 8192 + 2 * 512);
      bB3 = *(const half8*)(bt + 8192 + 3 * 512);
      {
        const int imm = dy * 5760;
        half8 af[4];
        #pragma unroll
        for (int mi = 0; mi < 4; ++mi) af[mi] = *(const half8*)(sb + abase[mi] + imm);
        #pragma unroll
        for (int mi = 0; mi < 4; ++mi) {
          acc[mi][0] = __builtin_amdgcn_mfma_f32_16x16x32_f16(af[mi], bA0, acc[mi][0], 0, 0, 0);
          acc[mi][1] = __builtin_amdgcn_mfma_f32_16x16x32_f16(af[mi], bA1, acc[mi][1], 0, 0, 0);
          acc[mi][2] = __builtin_amdgcn_mfma_f32_16x16x32_f16(af[mi], bA2, acc[mi][2], 0, 0, 0);
          acc[mi][3] = __builtin_amdgcn_mfma_f32_16x16x32_f16(af[mi], bA3, acc[mi][3], 0, 0, 0);
        }
      }
      // ---- dx = 1 (use B-set, prefetch A-set for dx=2) ----
      bA0 = *(const half8*)(bt + 16384 + 0 * 512);
      bA1 = *(const half8*)(bt + 16384 + 1 * 512);
      bA2 = *(const half8*)(bt + 16384 + 2 * 512);
      bA3 = *(const half8*)(bt + 16384 + 3 * 512);
      {
        const int imm = dy * 5760 + 576;
        half8 af[4];
        #pragma unroll
        for (int mi = 0; mi < 4; ++mi) af[mi] = *(const half8*)(sb + abase[mi] + imm);
        #pragma unroll
        for (int mi = 0; mi < 4; ++mi) {
          acc[mi][0] = __builtin_amdgcn_mfma_f32_16x16x32_f16(af[mi], bB0, acc[mi][0], 0, 0, 0);
          acc[mi][1] = __builtin_amdgcn_mfma_f32_16x16x32_f16(af[mi], bB1, acc[mi][1], 0, 0, 0);
          acc[mi][2] = __builtin_amdgcn_mfma_f32_16x16x32_f16(af[mi], bB2, acc[mi][2], 0, 0, 0);
          acc[mi][3] = __builtin_amdgcn_mfma_f32_16x16x32_f16(af[mi], bB3, acc[mi][3], 0, 0, 0);
        }
      }
      // ---- dx = 2 (use A-set) ----
      {
        const int imm = dy * 5760 + 1152;
        half8 af[4];
        #pragma unroll
        for (int mi = 0; mi < 4; ++mi) af[mi] = *(const half8*)(sb + abase[mi] + imm);
        #pragma unroll
        for (int mi = 0; mi < 4; ++mi) {
          acc[mi][0] = __builtin_amdgcn_mfma_f32_16x16x32_f16(af[mi], bA0, acc[mi][0], 0, 0, 0);
          acc[mi][1] = __builtin_amdgcn_mfma_f32_16x16x32_f16(af[mi], bA1, acc[mi][1], 0, 0, 0);
          acc[mi][2] = __builtin_amdgcn_mfma_f32_16x16x32_f16(af[mi], bA2, acc[mi][2], 0, 0, 0);
          acc[mi][3] = __builtin_amdgcn_mfma_f32_16x16x32_f16(af[mi], bA3, acc[mi][3], 0, 0, 0);
        }
      }
    }

    if (have && stager) {
      unsigned char* dst = lds + ((dz + 1) & 1) * 17280 + sR * 72;
      #pragma unroll
      for (int j = 0; j < 4; ++j) *(half8*)(dst + j * 16) = h[j];
    }
    __syncthreads();
  }

  // ---- store votes fp16 directly from acc (no LDS round-trip) ----
  // GEMM row m = pl*8+ic -> vote element (wg*64 + m)*256 + n
  _Float16* vb = vws + (size_t)wg * 64 * 256;
  const int rowb = (lane >> 4) * 4;
  const int colb = w * 64 + (lane & 15);
  #pragma unroll
  for (int mi = 0; mi < 4; ++mi)
    #pragma unroll
    for (int ni = 0; ni < 4; ++ni)
      #pragma unroll
      for (int j = 0; j < 4; ++j)
        vb[(mi * 16 + rowb + j) * 256 + colb + ni * 16] = (_Float16)acc[mi][ni][j];
}

// ================= kernel B: routing (r9 wave-local, verbatim math) =========
__global__ __launch_bounds__(256, 4)
void caps_route(const _Float16* __restrict__ vws, const float* __restrict__ bg,
                float* __restrict__ outg) {
  // per-wave 8x8 logits table, double-buffered (r9 protocol)
  __shared__ float smL[4 * 128];

  const int t    = threadIdx.x;
  const int lane = t & 63;
  const int w    = t >> 6;
  const int grow = blockIdx.x * 4 + w;      // global position row 0..27647

  const int ch = lane >> 5;
  const int al = lane & 31;
  float* smLw = smL + w * 128;

  float bia[4];
  #pragma unroll
  for (int q = 0; q < 4; ++q) bia[q] = bg[(2 * q + ch) * 32 + al];

  // votes: v[ic][q] = vws[(grow*8+ic)*256 + (2q+ch)*32+al]  (coalesced 128B/(ic,q))
  const _Float16* vp = vws + (size_t)grow * 8 * 256;
  float v[8][4];
  #pragma unroll
  for (int ic = 0; ic < 8; ++ic)
    #pragma unroll
    for (int q = 0; q < 4; ++q)
      v[ic][q] = (float)vp[ic * 256 + (2 * q + ch) * 32 + al];

  #pragma unroll 1
  for (int it = 0; it < 3; ++it) {
    const float* Lrd = smLw + ((it + 1) & 1) * 64;   // it=1 -> buf0, it=2 -> buf1
    float pre[4];
    #pragma unroll
    for (int q = 0; q < 4; ++q) pre[q] = bia[q];
    if (it == 0) {
      #pragma unroll
      for (int ic = 0; ic < 8; ++ic)
        #pragma unroll
        for (int q = 0; q < 4; ++q)
          pre[q] = fmaf(0.125f, v[ic][q], pre[q]);
    } else {
      #pragma unroll
      for (int ic = 0; ic < 8; ++ic) {
        const float4 La = *(const float4*)(Lrd + ic * 8);
        const float4 Lb = *(const float4*)(Lrd + ic * 8 + 4);
        const float Lv[8] = {La.x, La.y, La.z, La.w, Lb.x, Lb.y, Lb.z, Lb.w};
        float mx = Lv[0];
        #pragma unroll
        for (int cc = 1; cc < 8; ++cc) mx = fmaxf(mx, Lv[cc]);
        float e[8];
        float s = 0.f;
        #pragma unroll
        for (int cc = 0; cc < 8; ++cc) { e[cc] = __expf(Lv[cc] - mx); s += e[cc]; }
        const float inv = 1.0f / s;
        #pragma unroll
        for (int q = 0; q < 4; ++q)
          pre[q] = fmaf(e[2 * q + ch] * inv, v[ic][q], pre[q]);
      }
    }

    float act[4];
    #pragma unroll
    for (int q = 0; q < 4; ++q) {
      float ns = redhalf(pre[q] * pre[q]);
      act[q] = pre[q] * (sqrtf(ns) / (1.0f + ns));
    }

    if (it == 2) {
      #pragma unroll
      for (int q = 0; q < 4; ++q)
        outg[(size_t)grow * 256 + (2 * q + ch) * 32 + al] = act[q];
    } else {
      float d[8][4];
      #pragma unroll
      for (int ic = 0; ic < 8; ++ic)
        #pragma unroll
        for (int q = 0; q < 4; ++q)
          d[ic][q] = redhalf(v[ic][q] * act[q]);
      float* Lwr = smLw + (it & 1) * 64;
      if (al == 0) {
        #pragma unroll
        for (int ic = 0; ic < 8; ++ic)
          #pragma unroll
          for (int q = 0; q < 4; ++q) {
            const int cc = 2 * q + ch;
            Lwr[ic * 8 + cc] = (it == 0) ? d[ic][q] : Lrd[ic * 8 + cc] + d[ic][q];
          }
      }
      __syncthreads();
    }
  }
}

// ============ fused fallback: round-9 verified kernel (355us) ===============
__global__ __launch_bounds__(256, 4)
void caps_mfma7(const float* __restrict__ xg, const _Float16* __restrict__ Wh,
                const float* __restrict__ bg, float* __restrict__ outg) {
  __shared__ __align__(16) unsigned char lds[35840];
  float* smV = (float*)lds;

  const int t    = threadIdx.x;
  const int lane = t & 63;
  const int w    = t >> 6;
  const int wg   = (blockIdx.x & 7) * 432 + (blockIdx.x >> 3);
  const int rbase = wg * 8;
  const int b2   = rbase / SPT;
  const int posb = rbase % SPT;
  const int z  = posb / 576;
  const int y  = (posb % 576) / 24;
  const int x0 = posb % 24;

  const bool stager = t < 240;
  const int sdy  = t / 80;
  const int srem = t % 80;
  const int sxs  = srem >> 3;
  const int sic  = srem & 7;
  const int sn   = b2 * 8 + sic;
  const int sbin = sn & 1;
  const int sicin = sn >> 1;
  const int syy  = y + sdy - 1;
  const int sxx  = x0 + sxs - 1;
  const int sR   = (sdy * 10 + sxs) * 8 + sic;
  const bool syx_ok = (unsigned)syy < 24u && (unsigned)sxx < 24u;
  const float* sbase = xg + (((sbin * 24) * 24 + (syx_ok ? syy : 0)) * 24 + (syx_ok ? sxx : 0)) * 256 + sicin * 32;

  const int lm = lane & 15;
  int abase[4];
  #pragma unroll
  for (int mi = 0; mi < 4; ++mi)
    abase[mi] = ((mi * 2 + (lm >> 3)) * 8 + (lane & 7)) * 72 + (lane >> 4) * 16;

  const _Float16* bbase = Wh + w * 2048 + lane * 8;

  f32x4 acc[4][4];
  #pragma unroll
  for (int mi = 0; mi < 4; ++mi)
    #pragma unroll
    for (int ni = 0; ni < 4; ++ni) acc[mi][ni] = (f32x4){0.f, 0.f, 0.f, 0.f};

  {
    const int zz = z - 1;
    const bool val = (unsigned)zz < 24u && syx_ok;
    const float* src = sbase + (zz >= 0 ? zz : 0) * 24 * 24 * 256;
    half8 h[4];
    #pragma unroll
    for (int j = 0; j < 4; ++j) {
      float4 qa = val ? *(const float4*)(src + j * 8)     : (float4){0,0,0,0};
      float4 qb = val ? *(const float4*)(src + j * 8 + 4) : (float4){0,0,0,0};
      half8 hh;
      hh[0]=(_Float16)qa.x; hh[1]=(_Float16)qa.y; hh[2]=(_Float16)qa.z; hh[3]=(_Float16)qa.w;
      hh[4]=(_Float16)qb.x; hh[5]=(_Float16)qb.y; hh[6]=(_Float16)qb.z; hh[7]=(_Float16)qb.w;
      h[j] = hh;
    }
    if (stager) {
      unsigned char* dst = lds + sR * 72;
      #pragma unroll
      for (int j = 0; j < 4; ++j) *(half8*)(dst + j * 16) = h[j];
    }
  }
  __syncthreads();

  #pragma unroll 1
  for (int dz = 0; dz < 3; ++dz) {
    half8 h[4];
    const bool have = dz < 2;
    {
      const int zz = z + dz;
      const bool val = have && (unsigned)zz < 24u && syx_ok;
      const float* src = sbase + zz * 24 * 24 * 256;
      #pragma unroll
      for (int j = 0; j < 4; ++j) {
        float4 qa = val ? *(const float4*)(src + j * 8)     : (float4){0,0,0,0};
        float4 qb = val ? *(const float4*)(src + j * 8 + 4) : (float4){0,0,0,0};
        half8 hh;
        hh[0]=(_Float16)qa.x; hh[1]=(_Float16)qa.y; hh[2]=(_Float16)qa.z; hh[3]=(_Float16)qa.w;
        hh[4]=(_Float16)qb.x; hh[5]=(_Float16)qb.y; hh[6]=(_Float16)qb.z; hh[7]=(_Float16)qb.w;
        h[j] = hh;
      }
    }

    const unsigned char* sb = lds + (dz & 1) * 17280;
    #pragma unroll 1
    for (int dy = 0; dy < 3; ++dy) {
      const _Float16* bt = bbase + (dz * 9 + dy * 3) * 8192;
      half8 bA0, bA1, bA2, bA3, bB0, bB1, bB2, bB3;
      bA0 = *(const half8*)(bt + 0 * 512);
      bA1 = *(const half8*)(bt + 1 * 512);
      bA2 = *(const half8*)(bt + 2 * 512);
      bA3 = *(const half8*)(bt + 3 * 512);

      bB0 = *(const half8*)(bt + 8192 + 0 * 512);
      bB1 = *(const half8*)(bt + 8192 + 1 * 512);
      bB2 = *(const half8*)(bt + 8192 + 2 * 512);
      bB3 = *(const half8*)(bt + 8192 + 3 * 512);
      {
        const int imm = dy * 5760;
        half8 af[4];
        #pragma unroll
        for (int mi = 0; mi < 4; ++mi) af[mi] = *(const half8*)(sb + abase[mi] + imm);
        #pragma unroll
        for (int mi = 0; mi < 4; ++mi) {
          acc[mi][0] = __builtin_amdgcn_mfma_f32_16x16x32_f16(af[mi], bA0, acc[mi][0], 0, 0, 0);
          acc[mi][1] = __builtin_amdgcn_mfma_f32_16x16x32_f16(af[mi], bA1, acc[mi][1], 0, 0, 0);
          acc[mi][2] = __builtin_amdgcn_mfma_f32_16x16x32_f16(af[mi], bA2, acc[mi][2], 0, 0, 0);
          acc[mi][3] = __builtin_amdgcn_mfma_f32_16x16x32_f16(af[mi], bA3, acc[mi][3], 0, 0, 0);
        }
      }
      bA0 = *(const half8*)(bt + 16384 + 0 * 512);
      bA1 = *(const half8*)(bt + 16384 + 1 * 512);
      bA2 = *(const half8*)(bt + 16384 + 2 * 512);
      bA3 = *(const half8*)(bt + 16384 + 3 * 512);
      {
        const int imm = dy * 5760 + 576;
        half8 af[4];
        #pragma unroll
        for (int mi = 0; mi < 4; ++mi) af[mi] = *(const half8*)(sb + abase[mi] + imm);
        #pragma unroll
        for (int mi = 0; mi < 4; ++mi) {
          acc[mi][0] = __builtin_amdgcn_mfma_f32_16x16x32_f16(af[mi], bB0, acc[mi][0], 0, 0, 0);
          acc[mi][1] = __builtin_amdgcn_mfma_f32_16x16x32_f16(af[mi], bB1, acc[mi][1], 0, 0, 0);
          acc[mi][2] = __builtin_amdgcn_mfma_f32_16x16x32_f16(af[mi], bB2, acc[mi][2], 0, 0, 0);
          acc[mi][3] = __builtin_amdgcn_mfma_f32_16x16x32_f16(af[mi], bB3, acc[mi][3], 0, 0, 0);
        }
      }
      {
        const int imm = dy * 5760 + 1152;
        half8 af[4];
        #pragma unroll
        for (int mi = 0; mi < 4; ++mi) af[mi] = *(const half8*)(sb + abase[mi] + imm);
        #pragma unroll
        for (int mi = 0; mi < 4; ++mi) {
          acc[mi][0] = __builtin_amdgcn_mfma_f32_16x16x32_f16(af[mi], bA0, acc[mi][0], 0, 0, 0);
          acc[mi][1] = __builtin_amdgcn_mfma_f32_16x16x32_f16(af[mi], bA1, acc[mi][1], 0, 0, 0);
          acc[mi][2] = __builtin_amdgcn_mfma_f32_16x16x32_f16(af[mi], bA2, acc[mi][2], 0, 0, 0);
          acc[mi][3] = __builtin_amdgcn_mfma_f32_16x16x32_f16(af[mi], bA3, acc[mi][3], 0, 0, 0);
        }
      }
    }

    if (have && stager) {
      unsigned char* dst = lds + ((dz + 1) & 1) * 17280 + sR * 72;
      #pragma unroll
      for (int j = 0; j < 4; ++j) *(half8*)(dst + j * 16) = h[j];
    }
    __syncthreads();
  }

  const int ch = lane >> 5;
  const int al = lane & 31;
  float* smLw = (float*)(lds + 33792) + w * 128;

  float bia[4];
  #pragma unroll
  for (int q = 0; q < 4; ++q) bia[q] = bg[(2 * q + ch) * 32 + al];

  #pragma unroll 1
  for (int pass = 0; pass < 2; ++pass) {
    #pragma unroll
    for (int mh = 0; mh < 2; ++mh) {
      const int mi = pass * 2 + mh;
      #pragma unroll
      for (int ni = 0; ni < 4; ++ni) {
        #pragma unroll
        for (int j = 0; j < 4; ++j) {
          const int rl  = mh * 16 + (lane >> 4) * 4 + j;
          const int col = w * 64 + ni * 16 + (lane & 15);
          smV[rl * 264 + col] = acc[mi][ni][j];
        }
      }
    }
    __syncthreads();

    float v[8][4];
    #pragma unroll
    for (int ic = 0; ic < 8; ++ic)
      #pragma unroll
      for (int q = 0; q < 4; ++q)
        v[ic][q] = smV[(w * 8 + ic) * 264 + (2 * q + ch) * 32 + al];

    #pragma unroll 1
    for (int it = 0; it < 3; ++it) {
      const float* Lrd = smLw + ((it + 1) & 1) * 64;
      float pre[4];
      #pragma unroll
      for (int q = 0; q < 4; ++q) pre[q] = bia[q];
      if (it == 0) {
        #pragma unroll
        for (int ic = 0; ic < 8; ++ic)
          #pragma unroll
          for (int q = 0; q < 4; ++q)
            pre[q] = fmaf(0.125f, v[ic][q], pre[q]);
      } else {
        #pragma unroll
        for (int ic = 0; ic < 8; ++ic) {
          const float4 La = *(const float4*)(Lrd + ic * 8);
          const float4 Lb = *(const float4*)(Lrd + ic * 8 + 4);
          const float Lv[8] = {La.x, La.y, La.z, La.w, Lb.x, Lb.y, Lb.z, Lb.w};
          float mx = Lv[0];
          #pragma unroll
          for (int cc = 1; cc < 8; ++cc) mx = fmaxf(mx, Lv[cc]);
          float e[8];
          float s = 0.f;
          #pragma unroll
          for (int cc = 0; cc < 8; ++cc) { e[cc] = __expf(Lv[cc] - mx); s += e[cc]; }
          const float inv = 1.0f / s;
          #pragma unroll
          for (int q = 0; q < 4; ++q)
            pre[q] = fmaf(e[2 * q + ch] * inv, v[ic][q], pre[q]);
        }
      }

      float act[4];
      #pragma unroll
      for (int q = 0; q < 4; ++q) {
        float ns = redhalf(pre[q] * pre[q]);
        act[q] = pre[q] * (sqrtf(ns) / (1.0f + ns));
      }

      if (it == 2) {
        const int pl = pass * 4 + w;
        #pragma unroll
        for (int q = 0; q < 4; ++q)
          outg[(rbase + pl) * 256 + (2 * q + ch) * 32 + al] = act[q];
      } else {
        float d[8][4];
        #pragma unroll
        for (int ic = 0; ic < 8; ++ic)
          #pragma unroll
          for (int q = 0; q < 4; ++q)
            d[ic][q] = redhalf(v[ic][q] * act[q]);
        float* Lwr = smLw + (it & 1) * 64;
        if (al == 0) {
          #pragma unroll
          for (int ic = 0; ic < 8; ++ic)
            #pragma unroll
            for (int q = 0; q < 4; ++q) {
              const int cc = 2 * q + ch;
              Lwr[ic * 8 + cc] = (it == 0) ? d[ic][q] : Lrd[ic * 8 + cc] + d[ic][q];
            }
        }
        __syncthreads();
      }
    }
  }
}

// ---------------- last-resort fp32 fallback ----------------
__global__ __launch_bounds__(256, 3)
void caps_fused(const float* __restrict__ xg, const float* __restrict__ Wg,
                const float* __restrict__ bg, float* __restrict__ outg) {
  __shared__ __align__(16) float sm[10432];
  float* smA = sm;
  float* smB = sm + 2176;
  float* smV = sm;
  float* smL = sm + 10368;

  const int t    = threadIdx.x;
  const int blk  = blockIdx.x;
  const int rbase = blk * 8;
  const int b2   = rbase / SPT;
  const int posb = rbase % SPT;
  const int z  = posb / 576;
  const int y  = (posb % 576) / 24;
  const int x0 = posb % 24;

  const int pix_t = t >> 4;
  const int oc_t  = t & 15;
  const int am    = t >> 2;
  const int acin  = (t & 3) * 8;
  const int a_pl  = am >> 3;
  const int a_n   = b2 * 8 + (am & 7);
  const int a_bin = a_n & 1;
  const int a_icin = a_n >> 1;

  float acc[4][16];
  #pragma unroll
  for (int i = 0; i < 4; ++i)
    #pragma unroll
    for (int j = 0; j < 16; ++j) acc[i][j] = 0.f;

  #pragma unroll 1
  for (int tap = 0; tap < 27; ++tap) {
    const int dz = tap / 9, dy = (tap % 9) / 3, dx = tap % 3;
    const int zz = z + dz - 1;
    const int yy = y + dy - 1;
    const int xx = x0 + a_pl + dx - 1;

    float4 va = {0.f, 0.f, 0.f, 0.f}, vb = {0.f, 0.f, 0.f, 0.f};
    if ((unsigned)zz < 24u && (unsigned)yy < 24u && (unsigned)xx < 24u) {
      const float* src = xg + ((((a_bin * 24 + zz) * 24 + yy) * 24 + xx) * 8 + a_icin) * 32 + acin;
      va = *(const float4*)src;
      vb = *(const float4*)(src + 4);
    }
    float4 wv[8];
    const float* wsrc = Wg + tap * 8192 + t * 4;
    #pragma unroll
    for (int k = 0; k < 8; ++k) wv[k] = *(const float4*)(wsrc + k * 1024);

    __syncthreads();
    smA[(acin + 0) * 68 + am] = va.x;
    smA[(acin + 1) * 68 + am] = va.y;
    smA[(acin + 2) * 68 + am] = va.z;
    smA[(acin + 3) * 68 + am] = va.w;
    smA[(acin + 4) * 68 + am] = vb.x;
    smA[(acin + 5) * 68 + am] = vb.y;
    smA[(acin + 6) * 68 + am] = vb.z;
    smA[(acin + 7) * 68 + am] = vb.w;
    #pragma unroll
    for (int k = 0; k < 8; ++k) *(float4*)&smB[k * 1024 + t * 4] = wv[k];
    __syncthreads();

    #pragma unroll 8
    for (int cin = 0; cin < 32; ++cin) {
      const float4 a4  = *(const float4*)&smA[cin * 68 + pix_t * 4];
      const float4 b0  = *(const float4*)&smB[cin * 256 + oc_t * 4];
      const float4 b1  = *(const float4*)&smB[cin * 256 + oc_t * 4 + 64];
      const float4 b2v = *(const float4*)&smB[cin * 256 + oc_t * 4 + 128];
      const float4 b3v = *(const float4*)&smB[cin * 256 + oc_t * 4 + 192];
      const float ar[4] = {a4.x, a4.y, a4.z, a4.w};
      #pragma unroll
      for (int i = 0; i < 4; ++i) {
        acc[i][0]  = fmaf(ar[i], b0.x,  acc[i][0]);
        acc[i][1]  = fmaf(ar[i], b0.y,  acc[i][1]);
        acc[i][2]  = fmaf(ar[i], b0.z,  acc[i][2]);
        acc[i][3]  = fmaf(ar[i], b0.w,  acc[i][3]);
        acc[i][4]  = fmaf(ar[i], b1.x,  acc[i][4]);
        acc[i][5]  = fmaf(ar[i], b1.y,  acc[i][5]);
        acc[i][6]  = fmaf(ar[i], b1.z,  acc[i][6]);
        acc[i][7]  = fmaf(ar[i], b1.w,  acc[i][7]);
        acc[i][8]  = fmaf(ar[i], b2v.x, acc[i][8]);
        acc[i][9]  = fmaf(ar[i], b2v.y, acc[i][9]);
        acc[i][10] = fmaf(ar[i], b2v.z, acc[i][10]);
        acc[i][11] = fmaf(ar[i], b2v.w, acc[i][11]);
        acc[i][12] = fmaf(ar[i], b3v.x, acc[i][12]);
        acc[i][13] = fmaf(ar[i], b3v.y, acc[i][13]);
        acc[i][14] = fmaf(ar[i], b3v.z, acc[i][14]);
        acc[i][15] = fmaf(ar[i], b3v.w, acc[i][15]);
      }
    }
  }
  __syncthreads();

  const int c = t >> 5;
  const int a = t & 31;
  const float bia = bg[t];

  #pragma unroll 1
  for (int pass = 0; pass < 2; ++pass) {
    if ((pix_t >> 3) == pass) {
      const int rl = (pix_t & 7) * 4;
      #pragma unroll
      for (int i = 0; i < 4; ++i) {
        #pragma unroll
        for (int jj = 0; jj < 4; ++jj) {
          float4 v4 = {acc[i][jj * 4 + 0], acc[i][jj * 4 + 1],
                       acc[i][jj * 4 + 2], acc[i][jj * 4 + 3]};
          *(float4*)&smV[(rl + i) * 256 + oc_t * 4 + jj * 64] = v4;
        }
      }
    }
    __syncthreads();

    #pragma unroll 1
    for (int pp = 0; pp < 4; ++pp) {
      const int pl = pass * 4 + pp;
      float v[8];
      #pragma unroll
      for (int ic = 0; ic < 8; ++ic) v[ic] = smV[(pp * 8 + ic) * 256 + t];

      float route[8];
      #pragma unroll 1
      for (int it = 0; it < 3; ++it) {
        if (it == 0) {
          #pragma unroll
          for (int ic = 0; ic < 8; ++ic) route[ic] = 0.125f;
        } else {
          #pragma unroll
          for (int ic = 0; ic < 8; ++ic) {
            float mx = -3.4e38f;
            #pragma unroll
            for (int cc = 0; cc < 8; ++cc) mx = fmaxf(mx, smL[ic * 8 + cc]);
            float s = 0.f;
            #pragma unroll
            for (int cc = 0; cc < 8; ++cc) s += __expf(smL[ic * 8 + cc] - mx);
            route[ic] = __expf(smL[ic * 8 + c] - mx) / s;
          }
        }
        float pre = bia;
        #pragma unroll
        for (int ic = 0; ic < 8; ++ic) pre = fmaf(route[ic], v[ic], pre);

        float ns = redhalf(pre * pre);
        const float nrm = sqrtf(ns);
        const float act = pre * (nrm / (1.0f + ns));

        if (it == 2) {
          outg[(rbase + pl) * 256 + t] = act;
        } else {
          float d[8];
          #pragma unroll
          for (int ic = 0; ic < 8; ++ic) d[ic] = redhalf(v[ic] * act);
          __syncthreads();
          if (a == 0) {
            #pragma unroll
            for (int ic = 0; ic < 8; ++ic)
              smL[ic * 8 + c] = (it == 0) ? d[ic] : smL[ic * 8 + c] + d[ic];
          }
          __syncthreads();
        }
      }
    }
    __syncthreads();
  }
}

extern "C" void kernel_launch(void* const* d_in, const int* in_sizes, int n_in,
                              void* d_out, int out_size, void* d_ws, size_t ws_size,
                              hipStream_t stream) {
  const float* x = (const float*)d_in[0];
  const float* W = (const float*)d_in[1];
  const float* b = (const float*)d_in[2];
  float* out = (float*)d_out;
  (void)in_sizes; (void)n_in; (void)out_size;

  const size_t need_wh    = 27u * 8192u * sizeof(_Float16);            // 442368 B
  const size_t need_split = need_wh + (size_t)27648 * 2048 * sizeof(_Float16); // +113.2 MB

  if (ws_size >= need_split) {
    _Float16* Wh  = (_Float16*)d_ws;
    _Float16* vws = (_Float16*)((unsigned char*)d_ws + need_wh);
    prep_W<<<dim3(27), dim3(256), 0, stream>>>(W, Wh);
    caps_conv<<<dim3(3456), dim3(256), 0, stream>>>(x, Wh, vws);
    caps_route<<<dim3(6912), dim3(256), 0, stream>>>(vws, b, out);
  } else if (ws_size >= need_wh) {
    _Float16* Wh = (_Float16*)d_ws;
    prep_W<<<dim3(27), dim3(256), 0, stream>>>(W, Wh);
    caps_mfma7<<<dim3(3456), dim3(256), 0, stream>>>(x, Wh, b, out);
  } else {
    caps_fused<<<dim3(3456), dim3(256), 0, stream>>>(x, W, b, out);
  }
}